// Round 10
// baseline (176.340 us; speedup 1.0000x reference)
//
#include <hip/hip_runtime.h>

// AdaptiveConv2d v11: conv reverted to v8's exact kernel (best measured).
// Prep split: standalone hyper kernel + half-width transpose blocks
// (2080 blocks, 4 waves each -> ~full-device residency; 8 float4/thread
// batch-issued; <=64 VGPR). Same verified swizzle pair + coalesced
// linear-granule stores. Attacks prep's measured 33%-occupancy latency
// limit by doubling resident parallelism.

typedef __bf16 bf16;
typedef __bf16 bf16x8 __attribute__((ext_vector_type(8)));
typedef float f32x4 __attribute__((ext_vector_type(4)));

#define NB 16
#define CI 64
#define CO 64
#define HH 128
#define WW 128
#define TS 16
#define HALO 18           // TS + 2
#define NPL (HALO * HALO) // 324 halo pixels (fallback path)
#define NKW 36864         // CO*CI*9
#define NROWS 36928
#define XHW 130           // bordered NHWC width/height
#define WT2_BYTES ((size_t)NB * 9 * 4096 * 2)       // 1,179,648
#define BIAS_BYTES 4096
#define XH_BYTES ((size_t)NB * XHW * XHW * CI * 2)  // 34,611,200
#define WS_NEED (WT2_BYTES + BIAS_BYTES + XH_BYTES)

typedef const __attribute__((address_space(1))) void* gas_ptr;
typedef __attribute__((address_space(3))) void* las_ptr;

// ---------------- hypernetwork (standalone) ----------------
// grid 145 x 256. Thread owns one W2 row, loops the 16 samples; kernel
// rows land pre-swizzled for the conv A-fragment:
//   elem off = ((b*9+tap)*8 + g*2 + kh)*512 + (q*16+m)*8 + j
__global__ __launch_bounds__(256)
void hyper_kernel(const float* __restrict__ z, const float* __restrict__ W0,
                  const float* __restrict__ b0, const float* __restrict__ W1,
                  const float* __restrict__ b1, const float* __restrict__ W2,
                  const float* __restrict__ b2, bf16* __restrict__ wt2,
                  float* __restrict__ biases) {
  __shared__ float h1s[NB][30];
  const int tid = threadIdx.x;
  if (tid < NB) {
    float h0[20];
    #pragma unroll
    for (int i = 0; i < 20; ++i) {
      float s = b0[i];
      #pragma unroll
      for (int j = 0; j < 16; ++j) s += W0[i * 16 + j] * z[tid * 16 + j];
      h0[i] = fmaxf(s, 0.f);
    }
    #pragma unroll
    for (int i = 0; i < 30; ++i) {
      float s = b1[i];
      #pragma unroll
      for (int j = 0; j < 20; ++j) s += W1[i * 20 + j] * h0[j];
      h1s[tid][i] = fmaxf(s, 0.f);
    }
  }
  __syncthreads();
  const int r = blockIdx.x * 256 + tid;
  if (r >= NROWS) return;
  float w2r[30];
  #pragma unroll
  for (int j = 0; j < 30; ++j) w2r[j] = W2[r * 30 + j];
  const float bb = b2[r];
  const bool isk = r < NKW;
  size_t base = 0;
  if (isk) {
    const int co = r / 576;
    const int rem = r - co * 576;
    const int ci = rem / 9;
    const int tap = rem - ci * 9;
    const int g = co >> 4, mm = co & 15;
    const int kh = ci >> 5, qq = (ci >> 3) & 3, jj = ci & 7;
    base = (size_t)(tap * 8 + g * 2 + kh) * 512 + (size_t)(qq * 16 + mm) * 8 + jj;
  }
  for (int b = 0; b < NB; ++b) {
    float s = bb;
    #pragma unroll
    for (int j = 0; j < 30; ++j) s += w2r[j] * h1s[b][j];
    s = fmaxf(s, 0.f);
    if (isk)
      wt2[(size_t)b * (9 * 4096) + base] = (bf16)s;
    else
      biases[b * CO + (r - NKW)] = s;
  }
}

// ---------------- transpose: x NCHW fp32 -> xh bordered NHWC bf16 ----------------
// grid 2080 = 16 samples x 65 row-pairs x 2 width-halves; 256 thr = 4 waves.
// Thread (lane=ci, w): 16 px of each of 2 rows = 8 float4, batch-issued.
// LDS bounce 2 x 8 KB with XOR-granule swizzle (conflict-free b16 writes,
// b128 reads); stores in linear granule order (fully coalesced), border
// zeros folded in.
__global__ __launch_bounds__(256, 8)
void xpose_kernel(const float* __restrict__ x, bf16* __restrict__ xh) {
  const int tid = threadIdx.x;
  const int bi = blockIdx.x;
  const int b = bi / 130;
  const int rem = bi - b * 130;
  const int pr = rem >> 1;   // row-pair 0..64
  const int h = rem & 1;     // width half
  const int yp0 = pr * 2;    // 0,2,..,128

  const int lane = tid & 63; // = ci
  const int w = tid >> 6;    // 0..3
  const int px0 = h * 64 + w * 16;

  bf16* row0 = xh + ((size_t)(b * XHW + yp0)) * XHW * CI;
  bf16* row1 = row0 + XHW * CI;

  __shared__ __align__(16) bf16 xls[2][64 * 64]; // 2 x 8 KB

  const bool z0 = (yp0 == 0);
  const bool z1 = (yp0 + 1 == XHW - 1);
  const float* xsrc = x + (((size_t)b * CI + lane) << 14) + px0;

  // batch-issue all 8 float4 (both rows) before any use
  float v0[16], v1[16];
  if (!z0) {
    const float* s0 = xsrc + ((size_t)(yp0 - 1) << 7);
    #pragma unroll
    for (int j = 0; j < 4; ++j)
      *reinterpret_cast<f32x4*>(&v0[4 * j]) =
          *reinterpret_cast<const f32x4*>(s0 + 4 * j);
  }
  if (!z1) {
    const float* s1 = xsrc + ((size_t)yp0 << 7);
    #pragma unroll
    for (int j = 0; j < 4; ++j)
      *reinterpret_cast<f32x4*>(&v1[4 * j]) =
          *reinterpret_cast<const f32x4*>(s1 + 4 * j);
  }

  const int gq = lane >> 3;        // ci octet
  const int bo = (lane & 7) << 1;  // byte within granule
  const bf16x8 zero8 = {};

  // row 0: convert + conflict-free b16 LDS writes (local pxl = w*16+p)
  if (!z0) {
    #pragma unroll
    for (int p = 0; p < 16; ++p) {
      const int pxl = w * 16 + p;
      *reinterpret_cast<bf16*>(reinterpret_cast<char*>(xls[0]) + (pxl << 7) +
                               ((gq ^ (pxl & 7)) << 4) + bo) = (bf16)v0[p];
    }
  }
  __syncthreads();
  // store row 0: 520 granules (65 pxp x 8), linear order -> coalesced
  #pragma unroll
  for (int k = 0; k < 3; ++k) {
    const int it = k * 256 + tid;
    if (it >= 65 * 8) break; // k=2: only tid<8
    const int pxp = h * 65 + (it >> 3);
    const int gr = it & 7;
    bf16x8 vv = zero8;
    if (!z0 && pxp >= 1 && pxp <= 128) {
      const int pxl = pxp - 1 - h * 64;
      vv = *reinterpret_cast<const bf16x8*>(
          reinterpret_cast<const char*>(xls[0]) + (pxl << 7) +
          ((gr ^ (pxl & 7)) << 4));
    }
    *reinterpret_cast<bf16x8*>(row0 + h * 4160 + it * 8) = vv;
  }

  // row 1: independent buffer, no barrier needed before writes
  if (!z1) {
    #pragma unroll
    for (int p = 0; p < 16; ++p) {
      const int pxl = w * 16 + p;
      *reinterpret_cast<bf16*>(reinterpret_cast<char*>(xls[1]) + (pxl << 7) +
                               ((gq ^ (pxl & 7)) << 4) + bo) = (bf16)v1[p];
    }
  }
  __syncthreads();
  #pragma unroll
  for (int k = 0; k < 3; ++k) {
    const int it = k * 256 + tid;
    if (it >= 65 * 8) break;
    const int pxp = h * 65 + (it >> 3);
    const int gr = it & 7;
    bf16x8 vv = zero8;
    if (!z1 && pxp >= 1 && pxp <= 128) {
      const int pxl = pxp - 1 - h * 64;
      vv = *reinterpret_cast<const bf16x8*>(
          reinterpret_cast<const char*>(xls[1]) + (pxl << 7) +
          ((gr ^ (pxl & 7)) << 4));
    }
    *reinterpret_cast<bf16x8*>(row1 + h * 4160 + it * 8) = vv;
  }
}

// ---------------- conv (v8 exact: implicit GEMM, bf16 MFMA) ----------------
// 1D grid 1024, XCD-swizzled (XCD k <- 2 complete samples). Block: 512
// thr = 8 waves, 1 sample x 16x16 px x all 64 co; wave wv rows {2wv,2wv+1},
// acc[4 co-groups][2 rows]. x tile: global_load_lds from xh, LDS granule
// e=(pl,g) sourced from xh granule (pl, g^(pl&7)) -> linear dest, swizzled
// conflict-free reads. Weights: double-buffered registers. ONE barrier.
__global__ __launch_bounds__(512, 4)
void conv_kernel(const bf16* __restrict__ xh, const bf16* __restrict__ wt2,
                 const float* __restrict__ bias, float* __restrict__ out) {
  __shared__ __align__(16) bf16 xt[2624 * 8]; // 41,984 B (2592 + tail pad)

  const int id = (blockIdx.x & 7) * 128 + (blockIdx.x >> 3); // bijective
  const int b = id >> 6;
  const int x0 = (id & 7) * TS;
  const int y0 = ((id >> 3) & 7) * TS;

  const int tid = threadIdx.x;
  const int lane = tid & 63;
  const int wv = tid >> 6; // 0..7
  const int m = lane & 15;
  const int q = lane >> 4;

  const char* wbase = (const char*)wt2 + (size_t)b * 73728 + lane * 16;

  // ---- prefetch tap-0 A-fragments (first into the vmem queue) ----
  bf16x8 abuf[2][4][2];
  #pragma unroll
  for (int i = 0; i < 4; ++i)
    #pragma unroll
    for (int kh = 0; kh < 2; ++kh)
      abuf[0][i][kh] =
          *reinterpret_cast<const bf16x8*>(wbase + (i * 2 + kh) * 1024);

  // ---- stage x tile: 2592 granules of 16B via global_load_lds ----
  {
    const char* xb =
        (const char*)xh + (((size_t)(b * XHW + y0)) * XHW + x0) * 128;
    #pragma unroll
    for (int k = 0; k < 5; ++k) {
      const int e = k * 512 + tid;
      const int pl = e >> 3;
      const int gs = (e & 7) ^ (pl & 7);
      const int py = (pl * 57) >> 10; // pl/18, exact for pl < 512
      const int px = pl - py * 18;
      __builtin_amdgcn_global_load_lds(
          (gas_ptr)(xb + ((py * XHW + px) << 7) + (gs << 4)),
          (las_ptr)((char*)xt + ((k * 512 + wv * 64) << 4)), 16, 0, 0);
    }
    if (wv == 0) { // tail: granules 2560..2591 (+32 clamped dups into pad)
      const int esrc = min(2560 + lane, 2591);
      const int pl = esrc >> 3;
      const int gs = (esrc & 7) ^ (pl & 7);
      const int py = (pl * 57) >> 10;
      const int px = pl - py * 18;
      __builtin_amdgcn_global_load_lds(
          (gas_ptr)(xb + ((py * XHW + px) << 7) + (gs << 4)),
          (las_ptr)((char*)xt + (2560 << 4)), 16, 0, 0);
    }
  }

  f32x4 acc[4][2];
  #pragma unroll
  for (int i = 0; i < 4; ++i) {
    acc[i][0] = (f32x4){0.f, 0.f, 0.f, 0.f};
    acc[i][1] = (f32x4){0.f, 0.f, 0.f, 0.f};
  }

  const int ty0 = wv * 2;

  __syncthreads(); // staging drained (vmcnt(0) implicit before barrier)

  #pragma unroll
  for (int tap = 0; tap < 9; ++tap) {
    const int cur = tap & 1, nxt = cur ^ 1; // compile-time after unroll
    if (tap < 8) { // prefetch next tap's A-frags; overlaps this tap's MFMAs
      const char* wt_n = wbase + (tap + 1) * 8192;
      #pragma unroll
      for (int i = 0; i < 4; ++i)
        #pragma unroll
        for (int kh = 0; kh < 2; ++kh)
          abuf[nxt][i][kh] =
              *reinterpret_cast<const bf16x8*>(wt_n + (i * 2 + kh) * 1024);
    }
    const int dy = (tap * 11) >> 5; // tap/3
    const int dx = tap - dy * 3;
    const int plb = (ty0 + dy) * 18 + dx + m;
    __builtin_amdgcn_s_setprio(1);
    #pragma unroll
    for (int kh = 0; kh < 2; ++kh) {
      const int qk = q + kh * 4;
      #pragma unroll
      for (int j = 0; j < 2; ++j) {
        const int pl = plb + j * 18;
        const bf16x8 bv = *reinterpret_cast<const bf16x8*>(
            reinterpret_cast<const char*>(xt) + (pl << 7) +
            ((qk ^ (pl & 7)) << 4));
        #pragma unroll
        for (int i = 0; i < 4; ++i)
          acc[i][j] = __builtin_amdgcn_mfma_f32_16x16x32_bf16(
              abuf[cur][i][kh], bv, acc[i][j], 0, 0, 0);
      }
    }
    __builtin_amdgcn_s_setprio(0);
  }

  // epilogue: D col = m (px), row = q*4+r (co in group); co = i*16 + q*4 + r
  const float* bp = bias + b * CO;
  float* ob = out + ((size_t)(b * CO) << 14) + (size_t)((y0 + ty0) * WW + x0 + m);
  #pragma unroll
  for (int i = 0; i < 4; ++i)
    #pragma unroll
    for (int j = 0; j < 2; ++j)
      #pragma unroll
      for (int r = 0; r < 4; ++r) {
        const int co = i * 16 + q * 4 + r;
        float v = acc[i][j][r] + bp[co];
        ob[((size_t)co << 14) + j * WW] = fmaxf(v, 0.f);
      }
}

// ---------------- fallback conv (v4, reads raw x; ws too small) ----------------
__global__ __launch_bounds__(512, 4)
void conv_fb(const float* __restrict__ x, const bf16* __restrict__ wt2,
             const float* __restrict__ bias, float* __restrict__ out) {
  __shared__ __align__(16) bf16 xt[NPL * 64];

  const int id = (blockIdx.x & 7) * 128 + (blockIdx.x >> 3);
  const int b = id >> 6;
  const int x0 = (id & 7) * TS;
  const int y0 = ((id >> 3) & 7) * TS;

  const int tid = threadIdx.x;
  const int lane = tid & 63;
  const int wv = tid >> 6;
  const int m = lane & 15;
  const int q = lane >> 4;

  const char* wbase = (const char*)wt2 + (size_t)b * 73728 + lane * 16;

  bf16x8 abuf[2][4][2];
  #pragma unroll
  for (int i = 0; i < 4; ++i)
    #pragma unroll
    for (int kh = 0; kh < 2; ++kh)
      abuf[0][i][kh] =
          *reinterpret_cast<const bf16x8*>(wbase + (i * 2 + kh) * 1024);

  const float* xb = x + ((size_t)b << 20);
  for (int t = 0; t < 6; ++t) {
    const int it = min(tid + t * 512, NPL * 8 - 1);
    const int cig = ((it >> 2) * 810) >> 16;
    const int pl = it - cig * 324;
    const int py = (pl * 57) >> 10;
    const int px = pl - py * 18;
    int gy = y0 + py - 1, gx = x0 + px - 1;
    const bool inb = ((unsigned)gy < (unsigned)HH) & ((unsigned)gx < (unsigned)WW);
    gy = min(max(gy, 0), HH - 1);
    gx = min(max(gx, 0), WW - 1);
    const float* src = xb + ((size_t)cig << 17) + (gy << 7) + gx;
    bf16x8 v8;
    #pragma unroll
    for (int j = 0; j < 8; ++j)
      v8[j] = inb ? (bf16)src[(size_t)j << 14] : (bf16)0.f;
    if (!(t == 5 && tid >= NPL * 8 - 5 * 512))
      *reinterpret_cast<bf16x8*>(reinterpret_cast<char*>(xt) + (pl << 7) +
                                 ((cig ^ (pl & 7)) << 4)) = v8;
  }

  f32x4 acc[4][2];
  #pragma unroll
  for (int i = 0; i < 4; ++i) {
    acc[i][0] = (f32x4){0.f, 0.f, 0.f, 0.f};
    acc[i][1] = (f32x4){0.f, 0.f, 0.f, 0.f};
  }
  const int ty0 = wv * 2;
  __syncthreads();

  #pragma unroll
  for (int tap = 0; tap < 9; ++tap) {
    const int cur = tap & 1, nxt = cur ^ 1;
    if (tap < 8) {
      const char* wt_n = wbase + (tap + 1) * 8192;
      #pragma unroll
      for (int i = 0; i < 4; ++i)
        #pragma unroll
        for (int kh = 0; kh < 2; ++kh)
          abuf[nxt][i][kh] =
              *reinterpret_cast<const bf16x8*>(wt_n + (i * 2 + kh) * 1024);
    }
    const int dy = (tap * 11) >> 5;
    const int dx = tap - dy * 3;
    const int plb = (ty0 + dy) * 18 + dx + m;
    __builtin_amdgcn_s_setprio(1);
    #pragma unroll
    for (int kh = 0; kh < 2; ++kh) {
      const int qk = q + kh * 4;
      #pragma unroll
      for (int j = 0; j < 2; ++j) {
        const int pl = plb + j * 18;
        const bf16x8 bv = *reinterpret_cast<const bf16x8*>(
            reinterpret_cast<const char*>(xt) + (pl << 7) +
            ((qk ^ (pl & 7)) << 4));
        #pragma unroll
        for (int i = 0; i < 4; ++i)
          acc[i][j] = __builtin_amdgcn_mfma_f32_16x16x32_bf16(
              abuf[cur][i][kh], bv, acc[i][j], 0, 0, 0);
      }
    }
    __builtin_amdgcn_s_setprio(0);
  }

  const float* bp = bias + b * CO;
  float* ob = out + ((size_t)(b * CO) << 14) + (size_t)((y0 + ty0) * WW + x0 + m);
  #pragma unroll
  for (int i = 0; i < 4; ++i)
    #pragma unroll
    for (int j = 0; j < 2; ++j)
      #pragma unroll
      for (int r = 0; r < 4; ++r) {
        const int co = i * 16 + q * 4 + r;
        float v = acc[i][j][r] + bp[co];
        ob[((size_t)co << 14) + j * WW] = fmaxf(v, 0.f);
      }
}

extern "C" void kernel_launch(void* const* d_in, const int* in_sizes, int n_in,
                              void* d_out, int out_size, void* d_ws,
                              size_t ws_size, hipStream_t stream) {
  const float* x = (const float*)d_in[0];
  const float* z = (const float*)d_in[1];
  const float* W0 = (const float*)d_in[2];
  const float* b0 = (const float*)d_in[3];
  const float* W1 = (const float*)d_in[4];
  const float* b1 = (const float*)d_in[5];
  const float* W2 = (const float*)d_in[6];
  const float* b2 = (const float*)d_in[7];
  float* out = (float*)d_out;

  bf16* wt2 = (bf16*)d_ws;
  float* biases = (float*)((char*)d_ws + WT2_BYTES);
  bf16* xh = (bf16*)((char*)d_ws + WT2_BYTES + BIAS_BYTES);

  hipLaunchKernelGGL(hyper_kernel, dim3((NROWS + 255) / 256), dim3(256), 0,
                     stream, z, W0, b0, W1, b1, W2, b2, wt2, biases);
  if (ws_size >= WS_NEED) {
    hipLaunchKernelGGL(xpose_kernel, dim3(NB * 65 * 2), dim3(256), 0, stream,
                       x, xh);
    hipLaunchKernelGGL(conv_kernel, dim3(1024), dim3(512), 0, stream, xh, wt2,
                       biases, out);
  } else { // workspace too small: v4 path
    hipLaunchKernelGGL(conv_fb, dim3(1024), dim3(512), 0, stream, x, wt2,
                       biases, out);
  }
}

// Round 11
// 174.316 us; speedup vs baseline: 1.0116x; 1.0116x over previous
//
#include <hip/hip_runtime.h>

// AdaptiveConv2d v12: prep = v8 exact (hyper fused with transpose — v9/v11
// proved splitting costs ~17us serial). Conv = v8 pattern but 16x8 tiles:
// 2048 blocks, 24.6KB LDS -> 4 blocks/CU resident (100% occupancy), 8
// generations deep so staging overlaps compute across blocks. Same verified
// swizzle pair / A-frag double-buffer / accumulation order.

typedef __bf16 bf16;
typedef __bf16 bf16x8 __attribute__((ext_vector_type(8)));
typedef float f32x4 __attribute__((ext_vector_type(4)));

#define NB 16
#define CI 64
#define CO 64
#define HH 128
#define WW 128
#define TS 16
#define HALO 18           // TS + 2
#define NPL (HALO * HALO) // 324 halo pixels (fallback path)
#define NKW 36864         // CO*CI*9
#define NROWS 36928
#define XHW 130           // bordered NHWC width/height
#define WT2_BYTES ((size_t)NB * 9 * 4096 * 2)       // 1,179,648
#define BIAS_BYTES 4096
#define XH_BYTES ((size_t)NB * XHW * XHW * CI * 2)  // 34,611,200
#define WS_NEED (WT2_BYTES + BIAS_BYTES + XH_BYTES)

typedef const __attribute__((address_space(1))) void* gas_ptr;
typedef __attribute__((address_space(3))) void* las_ptr;

// ---------------- prep: hypernetwork + x transpose (v8, unchanged) ----------------
__global__ __launch_bounds__(256, 4)
void prep_kernel(const float* __restrict__ x, const float* __restrict__ z,
                 const float* __restrict__ W0, const float* __restrict__ b0,
                 const float* __restrict__ W1, const float* __restrict__ b1,
                 const float* __restrict__ W2, const float* __restrict__ b2,
                 bf16* __restrict__ wt2, float* __restrict__ biases,
                 bf16* __restrict__ xh) {
  const int tid = threadIdx.x;
  if (blockIdx.x < 145) {
    __shared__ float h1s[NB][30];
    if (tid < NB) {
      float h0[20];
      #pragma unroll
      for (int i = 0; i < 20; ++i) {
        float s = b0[i];
        #pragma unroll
        for (int j = 0; j < 16; ++j) s += W0[i * 16 + j] * z[tid * 16 + j];
        h0[i] = fmaxf(s, 0.f);
      }
      #pragma unroll
      for (int i = 0; i < 30; ++i) {
        float s = b1[i];
        #pragma unroll
        for (int j = 0; j < 20; ++j) s += W1[i * 20 + j] * h0[j];
        h1s[tid][i] = fmaxf(s, 0.f);
      }
    }
    __syncthreads();
    const int r = blockIdx.x * 256 + tid;
    if (r >= NROWS) return;
    float w2r[30];
    #pragma unroll
    for (int j = 0; j < 30; ++j) w2r[j] = W2[r * 30 + j];
    const float bb = b2[r];
    const bool isk = r < NKW;
    size_t base = 0;
    if (isk) {
      const int co = r / 576;
      const int rem = r - co * 576;
      const int ci = rem / 9;
      const int tap = rem - ci * 9;
      const int g = co >> 4, mm = co & 15;
      const int kh = ci >> 5, qq = (ci >> 3) & 3, jj = ci & 7;
      base = (size_t)(tap * 8 + g * 2 + kh) * 512 + (size_t)(qq * 16 + mm) * 8 + jj;
    }
    for (int b = 0; b < NB; ++b) {
      float s = bb;
      #pragma unroll
      for (int j = 0; j < 30; ++j) s += w2r[j] * h1s[b][j];
      s = fmaxf(s, 0.f);
      if (isk)
        wt2[(size_t)b * (9 * 4096) + base] = (bf16)s;
      else
        biases[b * CO + (r - NKW)] = s;
    }
    return;
  }

  // ---- transpose blocks: one (b, row-pair yp0, yp0+1) ----
  const int bi = blockIdx.x - 145;
  const int b = bi / 65;
  const int pr = bi - b * 65;
  const int yp0 = pr * 2;

  const int w = tid >> 6, lane = tid & 63;
  const int px0 = w * 32;

  bf16* row0 = xh + ((size_t)(b * XHW + yp0)) * XHW * CI;
  bf16* row1 = row0 + XHW * CI;

  __shared__ __align__(16) bf16 xls[2][128 * 64]; // 2 x 16 KB

  const bool z0 = (yp0 == 0);
  const bool z1 = (yp0 + 1 == XHW - 1);
  const float* xsrc = x + (((size_t)b * CI + lane) << 14) + px0;

  float v0[32], v1[32];
  if (!z0) {
    const float* s0 = xsrc + ((size_t)(yp0 - 1) << 7);
    #pragma unroll
    for (int j = 0; j < 8; ++j)
      *reinterpret_cast<f32x4*>(&v0[4 * j]) =
          *reinterpret_cast<const f32x4*>(s0 + 4 * j);
  }
  if (!z1) {
    const float* s1 = xsrc + ((size_t)yp0 << 7);
    #pragma unroll
    for (int j = 0; j < 8; ++j)
      *reinterpret_cast<f32x4*>(&v1[4 * j]) =
          *reinterpret_cast<const f32x4*>(s1 + 4 * j);
  }

  const int gq = lane >> 3;
  const int bo = (lane & 7) << 1;
  const bf16x8 zero8 = {};

  if (!z0) {
    #pragma unroll
    for (int p = 0; p < 32; ++p) {
      const int pxl = px0 + p;
      *reinterpret_cast<bf16*>(reinterpret_cast<char*>(xls[0]) + (pxl << 7) +
                               ((gq ^ (pxl & 7)) << 4) + bo) = (bf16)v0[p];
    }
  }
  __syncthreads();
  #pragma unroll
  for (int k = 0; k < 5; ++k) {
    const int it = k * 256 + tid;
    if (it >= XHW * 8) break;
    const int pxp = it >> 3, gr = it & 7;
    bf16x8 vv = zero8;
    if (!z0 && pxp >= 1 && pxp <= 128) {
      const int px = pxp - 1;
      vv = *reinterpret_cast<const bf16x8*>(
          reinterpret_cast<const char*>(xls[0]) + (px << 7) +
          ((gr ^ (px & 7)) << 4));
    }
    *reinterpret_cast<bf16x8*>(row0 + it * 8) = vv;
  }

  if (!z1) {
    #pragma unroll
    for (int p = 0; p < 32; ++p) {
      const int pxl = px0 + p;
      *reinterpret_cast<bf16*>(reinterpret_cast<char*>(xls[1]) + (pxl << 7) +
                               ((gq ^ (pxl & 7)) << 4) + bo) = (bf16)v1[p];
    }
  }
  __syncthreads();
  #pragma unroll
  for (int k = 0; k < 5; ++k) {
    const int it = k * 256 + tid;
    if (it >= XHW * 8) break;
    const int pxp = it >> 3, gr = it & 7;
    bf16x8 vv = zero8;
    if (!z1 && pxp >= 1 && pxp <= 128) {
      const int px = pxp - 1;
      vv = *reinterpret_cast<const bf16x8*>(
          reinterpret_cast<const char*>(xls[1]) + (px << 7) +
          ((gr ^ (px & 7)) << 4));
    }
    *reinterpret_cast<bf16x8*>(row1 + it * 8) = vv;
  }
}

// ---------------- conv v12 (implicit GEMM, bf16 MFMA, 16x8 tiles) ----------------
// 1D grid 2048, XCD-swizzled (XCD k <- ids 256k..: 2 complete samples).
// Block: 512 thr = 8 waves, 1 sample x 16 px x 8 rows x all 64 co; wave wv
// owns output row y0+wv, acc[4 co-groups]. x tile: 10 rows x 18 px staged
// via global_load_lds (1440 granules + 96 clamped dups), linear dest +
// inverse-swizzled source + swizzled b128 reads (verified pair). Weights:
// A-frags double-buffered in registers from L2. ONE barrier.
__global__ __launch_bounds__(512, 4)
void conv_kernel(const bf16* __restrict__ xh, const bf16* __restrict__ wt2,
                 const float* __restrict__ bias, float* __restrict__ out) {
  __shared__ __align__(16) bf16 xt[1536 * 8]; // 24,576 B -> 4 blocks/CU

  const int id = (blockIdx.x & 7) * 256 + (blockIdx.x >> 3); // bijective
  const int b = id >> 7;
  const int rem = id & 127;
  const int x0 = (rem & 7) * TS;
  const int y0 = (rem >> 3) * 8;

  const int tid = threadIdx.x;
  const int lane = tid & 63;
  const int wv = tid >> 6; // 0..7
  const int m = lane & 15;
  const int q = lane >> 4;

  const char* wbase = (const char*)wt2 + (size_t)b * 73728 + lane * 16;

  // ---- prefetch tap-0 A-fragments (first into the vmem queue) ----
  bf16x8 abuf[2][4][2];
  #pragma unroll
  for (int i = 0; i < 4; ++i)
    #pragma unroll
    for (int kh = 0; kh < 2; ++kh)
      abuf[0][i][kh] =
          *reinterpret_cast<const bf16x8*>(wbase + (i * 2 + kh) * 1024);

  // ---- stage x tile: 10 rows x 18 px = 180 pl = 1440 granules via gll ----
  {
    const char* xb =
        (const char*)xh + (((size_t)(b * XHW + y0)) * XHW + x0) * 128;
    #pragma unroll
    for (int k = 0; k < 3; ++k) {
      const int e = k * 512 + tid;
      const int esrc = min(e, 1439); // k=2 tail: dup-clamp into LDS pad
      const int pl = esrc >> 3;
      const int gs = (esrc & 7) ^ (pl & 7);
      const int py = (pl * 57) >> 10; // pl/18, exact for pl < 512
      const int px = pl - py * 18;
      __builtin_amdgcn_global_load_lds(
          (gas_ptr)(xb + ((py * XHW + px) << 7) + (gs << 4)),
          (las_ptr)((char*)xt + ((k * 512 + wv * 64) << 4)), 16, 0, 0);
    }
  }

  f32x4 acc[4];
  #pragma unroll
  for (int i = 0; i < 4; ++i) acc[i] = (f32x4){0.f, 0.f, 0.f, 0.f};

  __syncthreads(); // staging drained (vmcnt(0) implicit before barrier)

  #pragma unroll
  for (int tap = 0; tap < 9; ++tap) {
    const int cur = tap & 1, nxt = cur ^ 1; // compile-time after unroll
    if (tap < 8) { // prefetch next tap's A-frags; overlaps this tap's MFMAs
      const char* wt_n = wbase + (tap + 1) * 8192;
      #pragma unroll
      for (int i = 0; i < 4; ++i)
        #pragma unroll
        for (int kh = 0; kh < 2; ++kh)
          abuf[nxt][i][kh] =
              *reinterpret_cast<const bf16x8*>(wt_n + (i * 2 + kh) * 1024);
    }
    const int dy = (tap * 11) >> 5; // tap/3
    const int dx = tap - dy * 3;
    const int pl = (wv + dy) * 18 + dx + m;
    __builtin_amdgcn_s_setprio(1);
    #pragma unroll
    for (int kh = 0; kh < 2; ++kh) {
      const int qk = q + kh * 4;
      const bf16x8 bv = *reinterpret_cast<const bf16x8*>(
          reinterpret_cast<const char*>(xt) + (pl << 7) +
          ((qk ^ (pl & 7)) << 4));
      #pragma unroll
      for (int i = 0; i < 4; ++i)
        acc[i] = __builtin_amdgcn_mfma_f32_16x16x32_bf16(abuf[cur][i][kh], bv,
                                                         acc[i], 0, 0, 0);
    }
    __builtin_amdgcn_s_setprio(0);
  }

  // epilogue: D col = m (px), row = q*4+r (co in group); co = i*16 + q*4 + r
  const float* bp = bias + b * CO;
  float* ob =
      out + ((size_t)(b * CO) << 14) + (size_t)((y0 + wv) * WW + x0 + m);
  #pragma unroll
  for (int i = 0; i < 4; ++i)
    #pragma unroll
    for (int r = 0; r < 4; ++r) {
      const int co = i * 16 + q * 4 + r;
      float v = acc[i][r] + bp[co];
      ob[(size_t)co << 14] = fmaxf(v, 0.f);
    }
}

// ---------------- fallback conv (v4, reads raw x; ws too small) ----------------
__global__ __launch_bounds__(512, 4)
void conv_fb(const float* __restrict__ x, const bf16* __restrict__ wt2,
             const float* __restrict__ bias, float* __restrict__ out) {
  __shared__ __align__(16) bf16 xt[NPL * 64];

  const int id = (blockIdx.x & 7) * 128 + (blockIdx.x >> 3);
  const int b = id >> 6;
  const int x0 = (id & 7) * TS;
  const int y0 = ((id >> 3) & 7) * TS;

  const int tid = threadIdx.x;
  const int lane = tid & 63;
  const int wv = tid >> 6;
  const int m = lane & 15;
  const int q = lane >> 4;

  const char* wbase = (const char*)wt2 + (size_t)b * 73728 + lane * 16;

  bf16x8 abuf[2][4][2];
  #pragma unroll
  for (int i = 0; i < 4; ++i)
    #pragma unroll
    for (int kh = 0; kh < 2; ++kh)
      abuf[0][i][kh] =
          *reinterpret_cast<const bf16x8*>(wbase + (i * 2 + kh) * 1024);

  const float* xb = x + ((size_t)b << 20);
  for (int t = 0; t < 6; ++t) {
    const int it = min(tid + t * 512, NPL * 8 - 1);
    const int cig = ((it >> 2) * 810) >> 16;
    const int pl = it - cig * 324;
    const int py = (pl * 57) >> 10;
    const int px = pl - py * 18;
    int gy = y0 + py - 1, gx = x0 + px - 1;
    const bool inb = ((unsigned)gy < (unsigned)HH) & ((unsigned)gx < (unsigned)WW);
    gy = min(max(gy, 0), HH - 1);
    gx = min(max(gx, 0), WW - 1);
    const float* src = xb + ((size_t)cig << 17) + (gy << 7) + gx;
    bf16x8 v8;
    #pragma unroll
    for (int j = 0; j < 8; ++j)
      v8[j] = inb ? (bf16)src[(size_t)j << 14] : (bf16)0.f;
    if (!(t == 5 && tid >= NPL * 8 - 5 * 512))
      *reinterpret_cast<bf16x8*>(reinterpret_cast<char*>(xt) + (pl << 7) +
                                 ((cig ^ (pl & 7)) << 4)) = v8;
  }

  f32x4 acc[4][2];
  #pragma unroll
  for (int i = 0; i < 4; ++i) {
    acc[i][0] = (f32x4){0.f, 0.f, 0.f, 0.f};
    acc[i][1] = (f32x4){0.f, 0.f, 0.f, 0.f};
  }
  const int ty0 = wv * 2;
  __syncthreads();

  #pragma unroll
  for (int tap = 0; tap < 9; ++tap) {
    const int cur = tap & 1, nxt = cur ^ 1;
    if (tap < 8) {
      const char* wt_n = wbase + (tap + 1) * 8192;
      #pragma unroll
      for (int i = 0; i < 4; ++i)
        #pragma unroll
        for (int kh = 0; kh < 2; ++kh)
          abuf[nxt][i][kh] =
              *reinterpret_cast<const bf16x8*>(wt_n + (i * 2 + kh) * 1024);
    }
    const int dy = (tap * 11) >> 5;
    const int dx = tap - dy * 3;
    const int plb = (ty0 + dy) * 18 + dx + m;
    __builtin_amdgcn_s_setprio(1);
    #pragma unroll
    for (int kh = 0; kh < 2; ++kh) {
      const int qk = q + kh * 4;
      #pragma unroll
      for (int j = 0; j < 2; ++j) {
        const int pl = plb + j * 18;
        const bf16x8 bv = *reinterpret_cast<const bf16x8*>(
            reinterpret_cast<const char*>(xt) + (pl << 7) +
            ((qk ^ (pl & 7)) << 4));
        #pragma unroll
        for (int i = 0; i < 4; ++i)
          acc[i][j] = __builtin_amdgcn_mfma_f32_16x16x32_bf16(
              abuf[cur][i][kh], bv, acc[i][j], 0, 0, 0);
      }
    }
    __builtin_amdgcn_s_setprio(0);
  }

  const float* bp = bias + b * CO;
  float* ob = out + ((size_t)(b * CO) << 14) + (size_t)((y0 + ty0) * WW + x0 + m);
  #pragma unroll
  for (int i = 0; i < 4; ++i)
    #pragma unroll
    for (int j = 0; j < 2; ++j)
      #pragma unroll
      for (int r = 0; r < 4; ++r) {
        const int co = i * 16 + q * 4 + r;
        float v = acc[i][j][r] + bp[co];
        ob[((size_t)co << 14) + j * WW] = fmaxf(v, 0.f);
      }
}

extern "C" void kernel_launch(void* const* d_in, const int* in_sizes, int n_in,
                              void* d_out, int out_size, void* d_ws,
                              size_t ws_size, hipStream_t stream) {
  const float* x = (const float*)d_in[0];
  const float* z = (const float*)d_in[1];
  const float* W0 = (const float*)d_in[2];
  const float* b0 = (const float*)d_in[3];
  const float* W1 = (const float*)d_in[4];
  const float* b1 = (const float*)d_in[5];
  const float* W2 = (const float*)d_in[6];
  const float* b2 = (const float*)d_in[7];
  float* out = (float*)d_out;

  bf16* wt2 = (bf16*)d_ws;
  float* biases = (float*)((char*)d_ws + WT2_BYTES);
  bf16* xh = (bf16*)((char*)d_ws + WT2_BYTES + BIAS_BYTES);

  if (ws_size >= WS_NEED) {
    hipLaunchKernelGGL(prep_kernel, dim3(145 + NB * 65), dim3(256), 0, stream,
                       x, z, W0, b0, W1, b1, W2, b2, wt2, biases, xh);
    hipLaunchKernelGGL(conv_kernel, dim3(2048), dim3(512), 0, stream, xh, wt2,
                       biases, out);
  } else { // workspace too small: v4 path
    hipLaunchKernelGGL(prep_kernel, dim3(145), dim3(256), 0, stream, x, z, W0,
                       b0, W1, b1, W2, b2, wt2, biases, xh);
    hipLaunchKernelGGL(conv_fb, dim3(1024), dim3(512), 0, stream, x, wt2,
                       biases, out);
  }
}

// Round 12
// 161.398 us; speedup vs baseline: 1.0926x; 1.0800x over previous
//
#include <hip/hip_runtime.h>

// AdaptiveConv2d v13: v8-exact structure (best measured, 159.0). One fix,
// applied twice: sched_barrier(0) fences force the batch-issue / double-
// buffer schedules that the compiler was silently undoing to save VGPRs
// (v12 evidence: prep VGPR=32, conv VGPR=64 — both too small for the
// declared in-flight state to exist). No data-flow change.

typedef __bf16 bf16;
typedef __bf16 bf16x8 __attribute__((ext_vector_type(8)));
typedef float f32x4 __attribute__((ext_vector_type(4)));

#define NB 16
#define CI 64
#define CO 64
#define HH 128
#define WW 128
#define TS 16
#define HALO 18           // TS + 2
#define NPL (HALO * HALO) // 324 halo pixels (fallback path)
#define NKW 36864         // CO*CI*9
#define NROWS 36928
#define XHW 130           // bordered NHWC width/height
#define WT2_BYTES ((size_t)NB * 9 * 4096 * 2)       // 1,179,648
#define BIAS_BYTES 4096
#define XH_BYTES ((size_t)NB * XHW * XHW * CI * 2)  // 34,611,200
#define WS_NEED (WT2_BYTES + BIAS_BYTES + XH_BYTES)

typedef const __attribute__((address_space(1))) void* gas_ptr;
typedef __attribute__((address_space(3))) void* las_ptr;

// ---------------- prep: hypernetwork + x transpose ----------------
// blocks 0..144: hyper. blocks 145+: one (b, row-pair) of xh
// [16][130][130][64] bf16 with zero border. All 16 float4 loads issued
// BEFORE the convert/LDS section — pinned by sched_barrier(0).
__global__ __launch_bounds__(256, 4)
void prep_kernel(const float* __restrict__ x, const float* __restrict__ z,
                 const float* __restrict__ W0, const float* __restrict__ b0,
                 const float* __restrict__ W1, const float* __restrict__ b1,
                 const float* __restrict__ W2, const float* __restrict__ b2,
                 bf16* __restrict__ wt2, float* __restrict__ biases,
                 bf16* __restrict__ xh) {
  const int tid = threadIdx.x;
  if (blockIdx.x < 145) {
    __shared__ float h1s[NB][30];
    if (tid < NB) {
      float h0[20];
      #pragma unroll
      for (int i = 0; i < 20; ++i) {
        float s = b0[i];
        #pragma unroll
        for (int j = 0; j < 16; ++j) s += W0[i * 16 + j] * z[tid * 16 + j];
        h0[i] = fmaxf(s, 0.f);
      }
      #pragma unroll
      for (int i = 0; i < 30; ++i) {
        float s = b1[i];
        #pragma unroll
        for (int j = 0; j < 20; ++j) s += W1[i * 20 + j] * h0[j];
        h1s[tid][i] = fmaxf(s, 0.f);
      }
    }
    __syncthreads();
    const int r = blockIdx.x * 256 + tid;
    if (r >= NROWS) return;
    float w2r[30];
    #pragma unroll
    for (int j = 0; j < 30; ++j) w2r[j] = W2[r * 30 + j];
    const float bb = b2[r];
    const bool isk = r < NKW;
    size_t base = 0;
    if (isk) {
      const int co = r / 576;
      const int rem = r - co * 576;
      const int ci = rem / 9;
      const int tap = rem - ci * 9;
      const int g = co >> 4, mm = co & 15;
      const int kh = ci >> 5, qq = (ci >> 3) & 3, jj = ci & 7;
      base = (size_t)(tap * 8 + g * 2 + kh) * 512 + (size_t)(qq * 16 + mm) * 8 + jj;
    }
    for (int b = 0; b < NB; ++b) {
      float s = bb;
      #pragma unroll
      for (int j = 0; j < 30; ++j) s += w2r[j] * h1s[b][j];
      s = fmaxf(s, 0.f);
      if (isk)
        wt2[(size_t)b * (9 * 4096) + base] = (bf16)s;
      else
        biases[b * CO + (r - NKW)] = s;
    }
    return;
  }

  // ---- transpose blocks: one (b, row-pair yp0, yp0+1) ----
  const int bi = blockIdx.x - 145;
  const int b = bi / 65;
  const int pr = bi - b * 65;
  const int yp0 = pr * 2;

  const int w = tid >> 6, lane = tid & 63;
  const int px0 = w * 32;

  bf16* row0 = xh + ((size_t)(b * XHW + yp0)) * XHW * CI;
  bf16* row1 = row0 + XHW * CI;

  __shared__ __align__(16) bf16 xls[2][128 * 64]; // 2 x 16 KB

  const bool z0 = (yp0 == 0);
  const bool z1 = (yp0 + 1 == XHW - 1);
  const float* xsrc = x + (((size_t)b * CI + lane) << 14) + px0;

  // issue ALL loads for both rows; sched_barrier pins them above any use
  float v0[32], v1[32];
  if (!z0) {
    const float* s0 = xsrc + ((size_t)(yp0 - 1) << 7);
    #pragma unroll
    for (int j = 0; j < 8; ++j)
      *reinterpret_cast<f32x4*>(&v0[4 * j]) =
          *reinterpret_cast<const f32x4*>(s0 + 4 * j);
  }
  if (!z1) {
    const float* s1 = xsrc + ((size_t)yp0 << 7);
    #pragma unroll
    for (int j = 0; j < 8; ++j)
      *reinterpret_cast<f32x4*>(&v1[4 * j]) =
          *reinterpret_cast<const f32x4*>(s1 + 4 * j);
  }
  __builtin_amdgcn_sched_barrier(0); // force true batch issue (16 in flight)

  const int gq = lane >> 3;
  const int bo = (lane & 7) << 1;
  const bf16x8 zero8 = {};

  if (!z0) {
    #pragma unroll
    for (int p = 0; p < 32; ++p) {
      const int pxl = px0 + p;
      *reinterpret_cast<bf16*>(reinterpret_cast<char*>(xls[0]) + (pxl << 7) +
                               ((gq ^ (pxl & 7)) << 4) + bo) = (bf16)v0[p];
    }
  }
  __syncthreads();
  #pragma unroll
  for (int k = 0; k < 5; ++k) {
    const int it = k * 256 + tid;
    if (it >= XHW * 8) break;
    const int pxp = it >> 3, gr = it & 7;
    bf16x8 vv = zero8;
    if (!z0 && pxp >= 1 && pxp <= 128) {
      const int px = pxp - 1;
      vv = *reinterpret_cast<const bf16x8*>(
          reinterpret_cast<const char*>(xls[0]) + (px << 7) +
          ((gr ^ (px & 7)) << 4));
    }
    *reinterpret_cast<bf16x8*>(row0 + it * 8) = vv;
  }

  if (!z1) {
    #pragma unroll
    for (int p = 0; p < 32; ++p) {
      const int pxl = px0 + p;
      *reinterpret_cast<bf16*>(reinterpret_cast<char*>(xls[1]) + (pxl << 7) +
                               ((gq ^ (pxl & 7)) << 4) + bo) = (bf16)v1[p];
    }
  }
  __syncthreads();
  #pragma unroll
  for (int k = 0; k < 5; ++k) {
    const int it = k * 256 + tid;
    if (it >= XHW * 8) break;
    const int pxp = it >> 3, gr = it & 7;
    bf16x8 vv = zero8;
    if (!z1 && pxp >= 1 && pxp <= 128) {
      const int px = pxp - 1;
      vv = *reinterpret_cast<const bf16x8*>(
          reinterpret_cast<const char*>(xls[1]) + (px << 7) +
          ((gr ^ (px & 7)) << 4));
    }
    *reinterpret_cast<bf16x8*>(row1 + it * 8) = vv;
  }
}

// ---------------- conv (v8 structure + forced A-frag double buffer) ----------------
// 1D grid 1024, XCD-swizzled. Block: 512 thr = 8 waves, 1 sample x 16x16
// px x all 64 co; wave wv rows {2wv,2wv+1}, acc[4 co-groups][2 rows].
// x tile via global_load_lds (linear dest + inverse-swizzled source +
// swizzled b128 reads). A-frag prefetch pinned ABOVE the MFMA cluster by
// sched_barrier(0) so the next tap's 8 loads are genuinely in flight
// during this tap's 16 MFMAs. ONE barrier.
__global__ __launch_bounds__(512, 4)
void conv_kernel(const bf16* __restrict__ xh, const bf16* __restrict__ wt2,
                 const float* __restrict__ bias, float* __restrict__ out) {
  __shared__ __align__(16) bf16 xt[2624 * 8]; // 41,984 B (2592 + tail pad)

  const int id = (blockIdx.x & 7) * 128 + (blockIdx.x >> 3); // bijective
  const int b = id >> 6;
  const int x0 = (id & 7) * TS;
  const int y0 = ((id >> 3) & 7) * TS;

  const int tid = threadIdx.x;
  const int lane = tid & 63;
  const int wv = tid >> 6; // 0..7
  const int m = lane & 15;
  const int q = lane >> 4;

  const char* wbase = (const char*)wt2 + (size_t)b * 73728 + lane * 16;

  // ---- prefetch tap-0 A-fragments (first into the vmem queue) ----
  bf16x8 abuf[2][4][2];
  #pragma unroll
  for (int i = 0; i < 4; ++i)
    #pragma unroll
    for (int kh = 0; kh < 2; ++kh)
      abuf[0][i][kh] =
          *reinterpret_cast<const bf16x8*>(wbase + (i * 2 + kh) * 1024);

  // ---- stage x tile: 2592 granules of 16B via global_load_lds ----
  {
    const char* xb =
        (const char*)xh + (((size_t)(b * XHW + y0)) * XHW + x0) * 128;
    #pragma unroll
    for (int k = 0; k < 5; ++k) {
      const int e = k * 512 + tid;
      const int pl = e >> 3;
      const int gs = (e & 7) ^ (pl & 7);
      const int py = (pl * 57) >> 10; // pl/18, exact for pl < 512
      const int px = pl - py * 18;
      __builtin_amdgcn_global_load_lds(
          (gas_ptr)(xb + ((py * XHW + px) << 7) + (gs << 4)),
          (las_ptr)((char*)xt + ((k * 512 + wv * 64) << 4)), 16, 0, 0);
    }
    if (wv == 0) { // tail: granules 2560..2591 (+32 clamped dups into pad)
      const int esrc = min(2560 + lane, 2591);
      const int pl = esrc >> 3;
      const int gs = (esrc & 7) ^ (pl & 7);
      const int py = (pl * 57) >> 10;
      const int px = pl - py * 18;
      __builtin_amdgcn_global_load_lds(
          (gas_ptr)(xb + ((py * XHW + px) << 7) + (gs << 4)),
          (las_ptr)((char*)xt + (2560 << 4)), 16, 0, 0);
    }
  }

  f32x4 acc[4][2];
  #pragma unroll
  for (int i = 0; i < 4; ++i) {
    acc[i][0] = (f32x4){0.f, 0.f, 0.f, 0.f};
    acc[i][1] = (f32x4){0.f, 0.f, 0.f, 0.f};
  }

  const int ty0 = wv * 2;

  __syncthreads(); // staging drained (vmcnt(0) implicit before barrier)

  #pragma unroll
  for (int tap = 0; tap < 9; ++tap) {
    const int cur = tap & 1, nxt = cur ^ 1; // compile-time after unroll
    if (tap < 8) { // prefetch next tap's A-frags; overlaps this tap's MFMAs
      const char* wt_n = wbase + (tap + 1) * 8192;
      #pragma unroll
      for (int i = 0; i < 4; ++i)
        #pragma unroll
        for (int kh = 0; kh < 2; ++kh)
          abuf[nxt][i][kh] =
              *reinterpret_cast<const bf16x8*>(wt_n + (i * 2 + kh) * 1024);
      // pin the prefetch issue ABOVE the MFMA cluster (defeats reg-pressure
      // sinking that was serializing the double buffer — v12 VGPR evidence)
      __builtin_amdgcn_sched_barrier(0);
    }
    const int dy = (tap * 11) >> 5; // tap/3
    const int dx = tap - dy * 3;
    const int plb = (ty0 + dy) * 18 + dx + m;
    __builtin_amdgcn_s_setprio(1);
    #pragma unroll
    for (int kh = 0; kh < 2; ++kh) {
      const int qk = q + kh * 4;
      #pragma unroll
      for (int j = 0; j < 2; ++j) {
        const int pl = plb + j * 18;
        const bf16x8 bv = *reinterpret_cast<const bf16x8*>(
            reinterpret_cast<const char*>(xt) + (pl << 7) +
            ((qk ^ (pl & 7)) << 4));
        #pragma unroll
        for (int i = 0; i < 4; ++i)
          acc[i][j] = __builtin_amdgcn_mfma_f32_16x16x32_bf16(
              abuf[cur][i][kh], bv, acc[i][j], 0, 0, 0);
      }
    }
    __builtin_amdgcn_s_setprio(0);
  }

  // epilogue: D col = m (px), row = q*4+r (co in group); co = i*16 + q*4 + r
  const float* bp = bias + b * CO;
  float* ob = out + ((size_t)(b * CO) << 14) + (size_t)((y0 + ty0) * WW + x0 + m);
  #pragma unroll
  for (int i = 0; i < 4; ++i)
    #pragma unroll
    for (int j = 0; j < 2; ++j)
      #pragma unroll
      for (int r = 0; r < 4; ++r) {
        const int co = i * 16 + q * 4 + r;
        float v = acc[i][j][r] + bp[co];
        ob[((size_t)co << 14) + j * WW] = fmaxf(v, 0.f);
      }
}

// ---------------- fallback conv (v4, reads raw x; ws too small) ----------------
__global__ __launch_bounds__(512, 4)
void conv_fb(const float* __restrict__ x, const bf16* __restrict__ wt2,
             const float* __restrict__ bias, float* __restrict__ out) {
  __shared__ __align__(16) bf16 xt[NPL * 64];

  const int id = (blockIdx.x & 7) * 128 + (blockIdx.x >> 3);
  const int b = id >> 6;
  const int x0 = (id & 7) * TS;
  const int y0 = ((id >> 3) & 7) * TS;

  const int tid = threadIdx.x;
  const int lane = tid & 63;
  const int wv = tid >> 6;
  const int m = lane & 15;
  const int q = lane >> 4;

  const char* wbase = (const char*)wt2 + (size_t)b * 73728 + lane * 16;

  bf16x8 abuf[2][4][2];
  #pragma unroll
  for (int i = 0; i < 4; ++i)
    #pragma unroll
    for (int kh = 0; kh < 2; ++kh)
      abuf[0][i][kh] =
          *reinterpret_cast<const bf16x8*>(wbase + (i * 2 + kh) * 1024);

  const float* xb = x + ((size_t)b << 20);
  for (int t = 0; t < 6; ++t) {
    const int it = min(tid + t * 512, NPL * 8 - 1);
    const int cig = ((it >> 2) * 810) >> 16;
    const int pl = it - cig * 324;
    const int py = (pl * 57) >> 10;
    const int px = pl - py * 18;
    int gy = y0 + py - 1, gx = x0 + px - 1;
    const bool inb = ((unsigned)gy < (unsigned)HH) & ((unsigned)gx < (unsigned)WW);
    gy = min(max(gy, 0), HH - 1);
    gx = min(max(gx, 0), WW - 1);
    const float* src = xb + ((size_t)cig << 17) + (gy << 7) + gx;
    bf16x8 v8;
    #pragma unroll
    for (int j = 0; j < 8; ++j)
      v8[j] = inb ? (bf16)src[(size_t)j << 14] : (bf16)0.f;
    if (!(t == 5 && tid >= NPL * 8 - 5 * 512))
      *reinterpret_cast<bf16x8*>(reinterpret_cast<char*>(xt) + (pl << 7) +
                                 ((cig ^ (pl & 7)) << 4)) = v8;
  }

  f32x4 acc[4][2];
  #pragma unroll
  for (int i = 0; i < 4; ++i) {
    acc[i][0] = (f32x4){0.f, 0.f, 0.f, 0.f};
    acc[i][1] = (f32x4){0.f, 0.f, 0.f, 0.f};
  }
  const int ty0 = wv * 2;
  __syncthreads();

  #pragma unroll
  for (int tap = 0; tap < 9; ++tap) {
    const int cur = tap & 1, nxt = cur ^ 1;
    if (tap < 8) {
      const char* wt_n = wbase + (tap + 1) * 8192;
      #pragma unroll
      for (int i = 0; i < 4; ++i)
        #pragma unroll
        for (int kh = 0; kh < 2; ++kh)
          abuf[nxt][i][kh] =
              *reinterpret_cast<const bf16x8*>(wt_n + (i * 2 + kh) * 1024);
    }
    const int dy = (tap * 11) >> 5;
    const int dx = tap - dy * 3;
    const int plb = (ty0 + dy) * 18 + dx + m;
    __builtin_amdgcn_s_setprio(1);
    #pragma unroll
    for (int kh = 0; kh < 2; ++kh) {
      const int qk = q + kh * 4;
      #pragma unroll
      for (int j = 0; j < 2; ++j) {
        const int pl = plb + j * 18;
        const bf16x8 bv = *reinterpret_cast<const bf16x8*>(
            reinterpret_cast<const char*>(xt) + (pl << 7) +
            ((qk ^ (pl & 7)) << 4));
        #pragma unroll
        for (int i = 0; i < 4; ++i)
          acc[i][j] = __builtin_amdgcn_mfma_f32_16x16x32_bf16(
              abuf[cur][i][kh], bv, acc[i][j], 0, 0, 0);
      }
    }
    __builtin_amdgcn_s_setprio(0);
  }

  const float* bp = bias + b * CO;
  float* ob = out + ((size_t)(b * CO) << 14) + (size_t)((y0 + ty0) * WW + x0 + m);
  #pragma unroll
  for (int i = 0; i < 4; ++i)
    #pragma unroll
    for (int j = 0; j < 2; ++j)
      #pragma unroll
      for (int r = 0; r < 4; ++r) {
        const int co = i * 16 + q * 4 + r;
        float v = acc[i][j][r] + bp[co];
        ob[((size_t)co << 14) + j * WW] = fmaxf(v, 0.f);
      }
}

extern "C" void kernel_launch(void* const* d_in, const int* in_sizes, int n_in,
                              void* d_out, int out_size, void* d_ws,
                              size_t ws_size, hipStream_t stream) {
  const float* x = (const float*)d_in[0];
  const float* z = (const float*)d_in[1];
  const float* W0 = (const float*)d_in[2];
  const float* b0 = (const float*)d_in[3];
  const float* W1 = (const float*)d_in[4];
  const float* b1 = (const float*)d_in[5];
  const float* W2 = (const float*)d_in[6];
  const float* b2 = (const float*)d_in[7];
  float* out = (float*)d_out;

  bf16* wt2 = (bf16*)d_ws;
  float* biases = (float*)((char*)d_ws + WT2_BYTES);
  bf16* xh = (bf16*)((char*)d_ws + WT2_BYTES + BIAS_BYTES);

  if (ws_size >= WS_NEED) {
    hipLaunchKernelGGL(prep_kernel, dim3(145 + NB * 65), dim3(256), 0, stream,
                       x, z, W0, b0, W1, b1, W2, b2, wt2, biases, xh);
    hipLaunchKernelGGL(conv_kernel, dim3(1024), dim3(512), 0, stream, xh, wt2,
                       biases, out);
  } else { // workspace too small: v4 path
    hipLaunchKernelGGL(prep_kernel, dim3(145), dim3(256), 0, stream, x, z, W0,
                       b0, W1, b1, W2, b2, wt2, biases, xh);
    hipLaunchKernelGGL(conv_fb, dim3(1024), dim3(512), 0, stream, x, wt2,
                       biases, out);
  }
}